// Round 2
// baseline (8816.801 us; speedup 1.0000x reference)
//
#include <hip/hip_runtime.h>
#include <math.h>

#define VOCAB  32000
#define EMBED  512
#define HIDDEN 1024
#define BATCH  16
#define SEQ    256
#define M_TOTAL (BATCH*SEQ)   // 4096
#define RNN_BLOCKS 256

// ---------------------------------------------------------------- init
__global__ void k_init(int* cnt) {
    if (threadIdx.x == 0)
        __hip_atomic_store(cnt, 0, __ATOMIC_RELAXED, __HIP_MEMORY_SCOPE_AGENT);
}

// ------------------------------------------------- K1: embed + xproj GEMM
// xproj[m][n] = sum_k emb[tok[m]][k] * Wxh[k][n] + bias[n]; tok==0 -> zero row
__global__ __launch_bounds__(256) void k_embed_xproj(
    const int* __restrict__ tok, const float* __restrict__ emb,
    const float* __restrict__ Wxh, const float* __restrict__ bias,
    float* __restrict__ xproj)
{
    __shared__ float At[16][68];   // [k][m] transposed A tile, padded
    __shared__ float Bt[16][68];   // [k][n]
    const int row0 = blockIdx.y * 64;
    const int col0 = blockIdx.x * 64;
    const int tid = threadIdx.x;
    const int tx = tid & 15, ty = tid >> 4;

    // staging roles
    const int am = tid >> 2, aq = tid & 3;   // A: row am (0..63), k-quad aq
    const int bn = tid & 15, bk = tid >> 4;  // B: k-row bk (0..15), n-quad bn

    const int tokid = tok[row0 + am];
    const float4* embrow = (tokid == 0) ? (const float4*)nullptr
                         : (const float4*)(emb + (size_t)tokid * EMBED);

    float acc[4][4] = {};

    for (int k0 = 0; k0 < EMBED; k0 += 16) {
        float4 av = make_float4(0.f, 0.f, 0.f, 0.f);
        if (embrow) av = embrow[(k0 >> 2) + aq];
        float4 bv = *(const float4*)(Wxh + (size_t)(k0 + bk) * HIDDEN + col0 + bn * 4);

        __syncthreads();
        At[aq*4+0][am] = av.x; At[aq*4+1][am] = av.y;
        At[aq*4+2][am] = av.z; At[aq*4+3][am] = av.w;
        *(float4*)&Bt[bk][bn*4] = bv;
        __syncthreads();

        #pragma unroll
        for (int k = 0; k < 16; ++k) {
            float4 a = *(const float4*)&At[k][ty*4];
            float4 b = *(const float4*)&Bt[k][tx*4];
            float aa[4] = {a.x, a.y, a.z, a.w};
            float bb[4] = {b.x, b.y, b.z, b.w};
            #pragma unroll
            for (int i = 0; i < 4; ++i)
                #pragma unroll
                for (int j = 0; j < 4; ++j)
                    acc[i][j] = fmaf(aa[i], bb[j], acc[i][j]);
        }
    }

    float4 bb = *(const float4*)(bias + col0 + tx*4);
    #pragma unroll
    for (int i = 0; i < 4; ++i) {
        const int row = row0 + ty*4 + i;
        float4 v = make_float4(acc[i][0] + bb.x, acc[i][1] + bb.y,
                               acc[i][2] + bb.z, acc[i][3] + bb.w);
        *(float4*)(xproj + (size_t)row * HIDDEN + col0 + tx*4) = v;
    }
}

// ------------------------------------------------- K2: persistent RNN scan
// 256 blocks, block bid owns output columns c0..c0+3 for all batches.
// Per step: h[b][c] = tanh(xproj[b][t][c] + sum_k h_prev[b][k]*Whh[k][c])
// thread (kc = tid&15, b = tid>>4) accumulates k = kc (mod 16), then 16-lane
// shuffle reduce. Grid barrier per step (counter in ws, zeroed each call).
__global__ __launch_bounds__(256) void k_rnn(
    const float* __restrict__ xproj, const float* __restrict__ Whh,
    float* __restrict__ hs, int* cnt)
{
    __shared__ float4 wl[HIDDEN];          // Whh[:, c0..c0+3], staged once
    const int bid = blockIdx.x;
    const int c0 = bid * 4;
    const int tid = threadIdx.x;
    const int kc = tid & 15, b = tid >> 4;

    for (int r = tid; r < HIDDEN; r += 256)
        wl[r] = *(const float4*)(Whh + (size_t)r * HIDDEN + c0);
    __syncthreads();

    for (int t = 0; t < SEQ; ++t) {
        float ax = 0.f, ay = 0.f, az = 0.f, aw = 0.f;
        if (t > 0) {
            const float* hp = hs + (size_t)(b * SEQ + t - 1) * HIDDEN;
            #pragma unroll 8
            for (int i = 0; i < 64; ++i) {
                const int k = kc + (i << 4);
                const float hv = hp[k];
                const float4 w = wl[k];
                ax = fmaf(hv, w.x, ax); ay = fmaf(hv, w.y, ay);
                az = fmaf(hv, w.z, az); aw = fmaf(hv, w.w, aw);
            }
        }
        #pragma unroll
        for (int off = 8; off >= 1; off >>= 1) {
            ax += __shfl_xor(ax, off); ay += __shfl_xor(ay, off);
            az += __shfl_xor(az, off); aw += __shfl_xor(aw, off);
        }
        if (kc == 0) {
            const size_t row = (size_t)b * SEQ + t;
            const float4 xp = *(const float4*)(xproj + row * HIDDEN + c0);
            float* dst = hs + row * HIDDEN + c0;
            // agent-scope stores: cross-XCD visible after the release below
            __hip_atomic_store(dst + 0, tanhf(xp.x + ax), __ATOMIC_RELAXED, __HIP_MEMORY_SCOPE_AGENT);
            __hip_atomic_store(dst + 1, tanhf(xp.y + ay), __ATOMIC_RELAXED, __HIP_MEMORY_SCOPE_AGENT);
            __hip_atomic_store(dst + 2, tanhf(xp.z + az), __ATOMIC_RELAXED, __HIP_MEMORY_SCOPE_AGENT);
            __hip_atomic_store(dst + 3, tanhf(xp.w + aw), __ATOMIC_RELAXED, __HIP_MEMORY_SCOPE_AGENT);
        }
        if (t < SEQ - 1) {
            __syncthreads();
            if (tid == 0) {
                __threadfence();
                __hip_atomic_fetch_add(cnt, 1, __ATOMIC_RELEASE, __HIP_MEMORY_SCOPE_AGENT);
                const int target = RNN_BLOCKS * (t + 1);
                while (__hip_atomic_load(cnt, __ATOMIC_ACQUIRE, __HIP_MEMORY_SCOPE_AGENT) < target)
                    __builtin_amdgcn_s_sleep(2);
            }
            __syncthreads();
        }
    }
}

// ------------------------------------------------- K3: logits GEMM (f32)
// out[m][n] = sum_k hs[m][k]*Wout[k][n] + bout[n]
// 128x128 tile, BK=16, 256 threads, 8x8 microtile (split 64/64 for LDS banks)
__global__ __launch_bounds__(256) void k_logits(
    const float* __restrict__ hs, const float* __restrict__ Wout,
    const float* __restrict__ bout, float* __restrict__ out)
{
    __shared__ float At[16][132];   // [k][m]
    __shared__ float Bt[16][132];   // [k][n]
    const int col0 = blockIdx.x * 128;
    const int row0 = blockIdx.y * 128;
    const int tid = threadIdx.x;
    const int tx = tid & 15, ty = tid >> 4;

    float acc[8][8] = {};

    for (int k0 = 0; k0 < HIDDEN; k0 += 16) {
        float4 av[2], bv[2];
        #pragma unroll
        for (int p = 0; p < 2; ++p) {
            const int idx = tid + p * 256;
            const int m = idx >> 2, q = idx & 3;
            av[p] = *(const float4*)(hs + (size_t)(row0 + m) * HIDDEN + k0 + q * 4);
            const int n4 = idx & 31, kk = idx >> 5;
            bv[p] = *(const float4*)(Wout + (size_t)(k0 + kk) * VOCAB + col0 + n4 * 4);
        }
        __syncthreads();
        #pragma unroll
        for (int p = 0; p < 2; ++p) {
            const int idx = tid + p * 256;
            const int m = idx >> 2, q = idx & 3;
            At[q*4+0][m] = av[p].x; At[q*4+1][m] = av[p].y;
            At[q*4+2][m] = av[p].z; At[q*4+3][m] = av[p].w;
            const int n4 = idx & 31, kk = idx >> 5;
            *(float4*)&Bt[kk][n4*4] = bv[p];
        }
        __syncthreads();

        #pragma unroll
        for (int k = 0; k < 16; ++k) {
            float a[8], b[8];
            *(float4*)&a[0] = *(const float4*)&At[k][ty*4];
            *(float4*)&a[4] = *(const float4*)&At[k][64 + ty*4];
            *(float4*)&b[0] = *(const float4*)&Bt[k][tx*4];
            *(float4*)&b[4] = *(const float4*)&Bt[k][64 + tx*4];
            #pragma unroll
            for (int i = 0; i < 8; ++i)
                #pragma unroll
                for (int j = 0; j < 8; ++j)
                    acc[i][j] = fmaf(a[i], b[j], acc[i][j]);
        }
    }

    const float4 blo = *(const float4*)(bout + col0 + tx*4);
    const float4 bhi = *(const float4*)(bout + col0 + 64 + tx*4);
    #pragma unroll
    for (int ih = 0; ih < 2; ++ih)
        #pragma unroll
        for (int i = 0; i < 4; ++i) {
            const int row = row0 + ih*64 + ty*4 + i;
            float* orow = out + (size_t)row * VOCAB + col0;
            const int r = ih*4 + i;
            float4 v0 = make_float4(acc[r][0] + blo.x, acc[r][1] + blo.y,
                                    acc[r][2] + blo.z, acc[r][3] + blo.w);
            float4 v1 = make_float4(acc[r][4] + bhi.x, acc[r][5] + bhi.y,
                                    acc[r][6] + bhi.z, acc[r][7] + bhi.w);
            *(float4*)(orow + tx*4) = v0;
            *(float4*)(orow + 64 + tx*4) = v1;
        }
}

// ----------------------------------------------------------------- launch
extern "C" void kernel_launch(void* const* d_in, const int* in_sizes, int n_in,
                              void* d_out, int out_size, void* d_ws, size_t ws_size,
                              hipStream_t stream) {
    const int*   tok  = (const int*)d_in[0];
    const float* emb  = (const float*)d_in[1];
    const float* Wxh  = (const float*)d_in[2];
    const float* Whh  = (const float*)d_in[3];
    const float* bias = (const float*)d_in[4];
    const float* Wout = (const float*)d_in[5];
    const float* bout = (const float*)d_in[6];
    float* out = (float*)d_out;

    char* ws = (char*)d_ws;
    int*   cnt   = (int*)ws;                                   // barrier counter
    float* xproj = (float*)(ws + 1024);                        // 4096x1024 f32
    float* hs    = (float*)(ws + 1024 + (size_t)M_TOTAL*HIDDEN*sizeof(float));

    hipLaunchKernelGGL(k_init, dim3(1), dim3(64), 0, stream, cnt);
    hipLaunchKernelGGL(k_embed_xproj, dim3(HIDDEN/64, M_TOTAL/64), dim3(256), 0, stream,
                       tok, emb, Wxh, bias, xproj);
    hipLaunchKernelGGL(k_rnn, dim3(RNN_BLOCKS), dim3(256), 0, stream,
                       xproj, Whh, hs, cnt);
    hipLaunchKernelGGL(k_logits, dim3(VOCAB/128, M_TOTAL/128), dim3(256), 0, stream,
                       hs, Wout, bout, out);
}